// Round 9
// baseline (93641.687 us; speedup 1.0000x reference)
//
#include <hip/hip_runtime.h>
#include <hip/hip_cooperative_groups.h>
#include <math.h>

namespace cg = cooperative_groups;

#define Bsz 256
#define Tsz 512
#define GSTR 258    // gate-accum row stride (floats): 2-way LDS alias only (free)
#define LOOP_END 515   // it = 0..514 (out column t=it-3 covers 0..511 in-loop)

using half8 = __attribute__((ext_vector_type(8))) _Float16;
using half4 = __attribute__((ext_vector_type(4))) _Float16;
using f32x4 = __attribute__((ext_vector_type(4))) float;

#define MFMA_V(acc, a, b) (acc) = __builtin_amdgcn_mfma_f32_16x16x32_f16((a), (b), (acc), 0, 0, 0)
#define INV2048 (1.0f / 2048.0f)

__device__ __forceinline__ float sigm(float v)   { return 1.0f / (1.0f + expf(-v)); }
__device__ __forceinline__ float tanh_f(float v) { float e = expf(2.0f * v); return 1.0f - 2.0f / (e + 1.0f); }

__device__ __forceinline__ void split8(const float* p, half8& hi, half8& lo) {
    float4 v0 = *(const float4*)p, v1 = *(const float4*)(p + 4);
    float vv[8] = {v0.x, v0.y, v0.z, v0.w, v1.x, v1.y, v1.z, v1.w};
    #pragma unroll
    for (int j = 0; j < 8; ++j) {
        hi[j] = (_Float16)vv[j];
        lo[j] = (_Float16)((vv[j] - (float)hi[j]) * 2048.0f);
    }
}

// Write-through stores (sc1): visible at the device-coherent point, no wbL2.
__device__ __forceinline__ void st_h4(_Float16* p, half4 v) {
    unsigned long long u;
    __builtin_memcpy(&u, &v, 8);
    __hip_atomic_store((unsigned long long*)(void*)p, u,
                       __ATOMIC_RELAXED, __HIP_MEMORY_SCOPE_AGENT);
}
__device__ __forceinline__ void st_f(float* p, float v) {
    __hip_atomic_store(p, v, __ATOMIC_RELAXED, __HIP_MEMORY_SCOPE_AGENT);
}
// L1/L2-bypassing coherent load (for the A->B gate-partial exchange buffer,
// which rotates on only 2 slots -> reader L2 could be stale between flushes).
__device__ __forceinline__ float agf_ld(const float* p) {
    return __hip_atomic_load(p, __ATOMIC_RELAXED, __HIP_MEMORY_SCOPE_AGENT);
}

__device__ __forceinline__ unsigned ag_add(unsigned* p, unsigned v) {
    return __hip_atomic_fetch_add(p, v, __ATOMIC_RELAXED, __HIP_MEMORY_SCOPE_AGENT);
}
__device__ __forceinline__ unsigned ag_ld(unsigned* p) {
    return __hip_atomic_load(p, __ATOMIC_RELAXED, __HIP_MEMORY_SCOPE_AGENT);
}

__device__ __forceinline__ void busy_fma(float& z) {
    #pragma unroll
    for (int i = 0; i < 16; ++i)
        z = __builtin_fmaf(z, 1.0000001f, 1e-9f);
    asm volatile("" :: "v"(z));
}

// ---------------------------------------------------------------------------
// Step barrier: R17's (passed). Hierarchical agent-scope arrival/release,
// wave-uniform busy-wait spin, leader wbL2+invL2 every 4th step.
// ---------------------------------------------------------------------------
__device__ __forceinline__ void step_barrier(unsigned* arrX, unsigned* flagX,
                                             unsigned* bar1, unsigned* dummyv,
                                             unsigned* relFlag,   // LDS
                                             int isLead, unsigned xcc,
                                             unsigned nLead, unsigned nBlkX,
                                             unsigned it1) {
    __syncthreads();   // all waves' stores drained (vmcnt 0) -> at coherent point
    if ((threadIdx.x >> 6) == 0) {          // wave 0 (uniform branch)
        if ((threadIdx.x & 63) == 0) {      // lane 0: the protocol
            float z = 1.0f;
            ag_add(&arrX[xcc << 5], 1u);
            if (isLead) {
                while (ag_ld(&arrX[xcc << 5]) < nBlkX * it1) busy_fma(z);
                ag_add(bar1, 1u);
                while (ag_ld(bar1) < nLead * it1) busy_fma(z);
                if ((it1 & 3u) == 0u)       // every 4th step: the ONE wbL2+invL2
                    __hip_atomic_fetch_add(&dummyv[xcc << 5], 1u,
                                           __ATOMIC_ACQ_REL, __HIP_MEMORY_SCOPE_AGENT);
                ag_add(&flagX[xcc << 5], 1u);
            } else {
                while (ag_ld(&flagX[xcc << 5]) < it1) busy_fma(z);
            }
            asm volatile("s_waitcnt vmcnt(0)" ::: "memory");
            __hip_atomic_store(relFlag, it1, __ATOMIC_RELAXED,
                               __HIP_MEMORY_SCOPE_WORKGROUP);
        }
        asm volatile("buffer_inv sc0" ::: "memory");
    } else {                                // waves 1..7
        float z = 1.0f + (float)(threadIdx.x & 63) * 1e-8f;
        while (__hip_atomic_load(relFlag, __ATOMIC_RELAXED,
                                 __HIP_MEMORY_SCOPE_WORKGROUP) < it1)
            busy_fma(z);
        asm volatile("buffer_inv sc0" ::: "memory");
    }
}

// ---------------------------------------------------------------------------
// R18: per-CU traffic halved via layer-2 split-K across block pairs.
// Roles: bx<128: L1 (unchanged; reads h1, 1MB/step).
//        128<=bx<192 (A): pih2(t)=W_ih2 rows . h1(t)  — reads ONLY h1 (1MB).
//        192<=bx<256 (B): phh2(t)=W_hh2 rows . h2(t-1) — reads ONLY h2 (1MB);
//                         B sums A's partial (xbuf) + own + bias, runs cell2.
// Pipeline: cell2(t) at step t+2 (was t+1); out(t) at step t+3. Layer-2 slack
// absorbs the shift: no extra barrier per step. Max per-CU bytes 2MB -> 1MB.
// ---------------------------------------------------------------------------
__global__ __launch_bounds__(512, 1) void lstm_persist(
    const float* __restrict__ x,
    const float* __restrict__ W_ih1, const float* __restrict__ W_hh1,
    const float* __restrict__ b_ih1, const float* __restrict__ b_hh1,
    const float* __restrict__ W_ih2, const float* __restrict__ W_hh2,
    const float* __restrict__ b_ih2, const float* __restrict__ b_hh2,
    const float* __restrict__ W_out, const float* __restrict__ b_out,
    float* __restrict__ out, char* __restrict__ ws)
{
    __shared__ float gAcc[64 * GSTR];   // gate accumulator [perm row][b] (A/B: 64 rows, L1: 32)
    __shared__ float bp[64], wihp[32], woutp[16];
    __shared__ float bouts_s;
    __shared__ unsigned isLead_s, xcc_s, nLead_s, nBlkX_s;
    __shared__ unsigned relFlag_s;

    cg::grid_group grid = cg::this_grid();

    const int tid  = threadIdx.x;
    const int lane = tid & 63;
    const int wv   = tid >> 6;
    const int m    = lane & 15;
    const int quad = lane >> 4;
    const int bx   = blockIdx.x;
    const int role = (bx < 128) ? 0 : (bx < 192 ? 1 : 2);   // L1 / A / B
    const int pa   = bx & 63;          // pair index for A/B
    const int HO1  = bx << 3;          // L1: 8 h1-units
    const int HO2  = pa << 4;          // A/B: 16 h2-units (64 gate rows)

    // ---- workspace --------------------------------------------------------
    float*    xT       = (float*)ws;                                  // [512][256]
    _Float16* hswz     = (_Float16*)(ws + (512 << 10));               // 16 x 512KB (4 slots x {h1,h2} x {hi,lo})
    float*    partials = (float*)(ws + (512 << 10) + (8 << 20));      // [4 slot][256 b][128 rg]
    unsigned* bar0     = (unsigned*)(ws + (9 << 20));
    unsigned* arrX     = bar0 + 512;
    unsigned* flagX    = bar0 + 768;
    unsigned* bar1     = bar0 + 1024;
    unsigned* nLeadCt  = bar0 + 1057;
    unsigned* claimA   = bar0 + 1088;
    unsigned* dummyv   = bar0 + 1536;
    float*    xbuf     = (float*)(ws + (10 << 20));   // [2 slot][64 pair][64 row][256 b] f32 = 8MB

    #define HBUF(p, l, hl) (hswz + ((((p) << 2) | ((l) << 1) | (hl)) << 18))

    // ---- pre-loop init ----------------------------------------------------
    if (bx == 0)
        for (int i = tid; i < 2048; i += 512) bar0[i] = 0u;
    if (role == 0 && tid < 32) {
        const int row = ((tid & 3) << 10) + HO1 + (tid >> 2);
        bp[tid]   = b_ih1[row] + b_hh1[row];
        wihp[tid] = W_ih1[row];
    }
    if (role == 2) {
        if (tid < 64) {
            const int row = ((tid & 3) << 10) + HO2 + (tid >> 2);
            bp[tid] = b_ih2[row] + b_hh2[row];
        }
        if (tid < 16) woutp[tid] = W_out[HO2 + tid];
    }
    if (tid == 0) { bouts_s = b_out[0]; relFlag_s = 0u; }
    {
        const int gidx = bx * 512 + tid;                 // 0..131071
        // zero slot-3 h region (h1(-1), h2(-1), hi+lo): bytes [6MB, 8MB)
        *(float4*)((char*)hswz + (6u << 20) + (size_t)gidx * 16) = make_float4(0, 0, 0, 0);
        xT[gidx] = x[(gidx & 255) * Tsz + (gidx >> 8)];
    }

    grid.sync();

    // ---- leader election by PHYSICAL XCD id -------------------------------
    if (tid == 0) {
        unsigned xcc;
        asm volatile("s_getreg_b32 %0, hwreg(HW_REG_XCC_ID)" : "=s"(xcc));
        xcc &= 7u;
        xcc_s = xcc;
        unsigned old = ag_add(&claimA[xcc << 5], 1u);
        isLead_s = (old == 0u);
        if (old == 0u) ag_add(nLeadCt, 1u);
    }
    grid.sync();
    if (tid == 0) {
        nLead_s = ag_ld(nLeadCt);
        nBlkX_s = ag_ld(&claimA[xcc_s << 5]);
    }
    __syncthreads();
    const int      isLead = (int)isLead_s;
    const unsigned xcc    = xcc_s;
    const unsigned nLead  = nLead_s;
    const unsigned nBlkX  = nBlkX_s;

    const int b_ep = tid & 255, hg = tid >> 8;

    if (role == 0) {
        // ==================== LAYER-1 BLOCKS (unchanged GEMM/cell) =========
        const int k0e  = HO1 + (hg << 2);
        const int wofs = ((b_ep >> 4) << 14) + ((k0e >> 5) << 9)
                       + (((b_ep & 15) | (((k0e >> 3) & 3) << 4)) << 3) + (k0e & 7);
        half8 wh[2][4], wl[2][4];     // 64 regs/wave, K-slice 128
        #pragma unroll
        for (int mt = 0; mt < 2; ++mt) {
            const int pr = (mt << 4) + m;
            const size_t rw = (size_t)(((pr & 3) << 10) + HO1 + (pr >> 2)) << 10;
            #pragma unroll
            for (int kt = 0; kt < 4; ++kt) {
                const int k = (wv << 7) + (kt << 5) + (quad << 3);
                split8(W_hh1 + rw + k, wh[mt][kt], wl[mt][kt]);
            }
        }
        for (int idx = tid; idx < 8192; idx += 512) {
            const int p = idx >> 8, b = idx & 255;
            gAcc[p * GSTR + b] = bp[p] + xT[b] * wihp[p];
        }
        __syncthreads();
        float cr[4] = {0, 0, 0, 0};

        for (int it = 0; it < LOOP_END; ++it) {
            const int sW = it & 3;
            const int sR = (it + 3) & 3;
            const int sP = it & 3;

            float xnext = 0.0f;
            if (it + 1 < Tsz) xnext = xT[((it + 1) << 8) + b_ep];

            if (wv == 0 && it >= 3) {                    // out column t=it-3
                const float* pp = partials + (sP << 15) + (bx << 7);
                float s = pp[lane] + pp[lane + 64];
                s += __shfl_xor(s, 32); s += __shfl_xor(s, 16); s += __shfl_xor(s, 8);
                s += __shfl_xor(s, 4);  s += __shfl_xor(s, 2);  s += __shfl_xor(s, 1);
                if (lane == 0) st_f(&out[(bx << 9) + (it - 3)], bouts_s + s);
            }

            if (it < Tsz) {            // gates1(it) += Whh1 . h1(it-1)
                const _Float16* bhB = HBUF(sR, 0, 0);
                const _Float16* blB = HBUF(sR, 0, 1);
                const int lo_off = (wv << 11) + (lane << 3);
                #pragma unroll 2
                for (int bi = 0; bi < 16; ++bi) {
                    const int btl = (bi + (wv << 1)) & 15;
                    const _Float16* ph = bhB + (btl << 14) + lo_off;
                    const _Float16* pl = blB + (btl << 14) + lo_off;
                    half8 bh[4], bl[4];
                    #pragma unroll
                    for (int kt = 0; kt < 4; ++kt) {
                        bh[kt] = *(const half8*)(ph + (kt << 9));
                        bl[kt] = *(const half8*)(pl + (kt << 9));
                    }
                    f32x4 a0[2] = {(f32x4){0,0,0,0}, (f32x4){0,0,0,0}};
                    f32x4 a1[2] = {(f32x4){0,0,0,0}, (f32x4){0,0,0,0}};
                    #pragma unroll
                    for (int kt = 0; kt < 4; ++kt) {
                        MFMA_V(a0[0], wh[0][kt], bh[kt]);
                        MFMA_V(a1[0], wh[0][kt], bl[kt]);
                        MFMA_V(a1[0], wl[0][kt], bh[kt]);
                        MFMA_V(a0[1], wh[1][kt], bh[kt]);
                        MFMA_V(a1[1], wh[1][kt], bl[kt]);
                        MFMA_V(a1[1], wl[1][kt], bh[kt]);
                    }
                    const int col = (btl << 4) + m;
                    #pragma unroll
                    for (int mt = 0; mt < 2; ++mt)
                        #pragma unroll
                        for (int r = 0; r < 4; ++r)
                            atomicAdd(&gAcc[((mt << 4) + (quad << 2) + r) * GSTR + col],
                                      a0[mt][r] + a1[mt][r] * INV2048);
                }
            }

            __syncthreads();

            if (it < Tsz) {            // layer-1 cell -> h1(it) @slot sW
                half4 hhi, hlo;
                #pragma unroll
                for (int j = 0; j < 4; ++j) {
                    const int p = (hg << 4) + (j << 2);
                    const float gi = gAcc[(p + 0) * GSTR + b_ep];
                    const float gf = gAcc[(p + 1) * GSTR + b_ep];
                    const float gg = gAcc[(p + 2) * GSTR + b_ep];
                    const float go = gAcc[(p + 3) * GSTR + b_ep];
                    const float c  = sigm(gf) * cr[j] + sigm(gi) * tanh_f(gg);
                    cr[j] = c;
                    const float hn = sigm(go) * tanh_f(c);
                    hhi[j] = (_Float16)hn;
                    hlo[j] = (_Float16)((hn - (float)hhi[j]) * 2048.0f);
                }
                st_h4(HBUF(sW, 0, 0) + wofs, hhi);
                st_h4(HBUF(sW, 0, 1) + wofs, hlo);
                if (it + 1 < Tsz) {
                    #pragma unroll
                    for (int p = (hg << 4); p < (hg << 4) + 16; ++p)
                        gAcc[p * GSTR + b_ep] = bp[p] + xnext * wihp[p];
                }
            }

            step_barrier(arrX, flagX, bar1, dummyv, &relFlag_s,
                         isLead, xcc, nLead, nBlkX, (unsigned)(it + 1));
        }
    } else if (role == 1) {
        // ==================== A BLOCKS: pih2(t=S-1) = W_ih2 . h1(S-1) ======
        half8 wh[4][4], wl[4][4];     // 128 regs/wave, M=64 rows, K-slice 128
        #pragma unroll
        for (int mt = 0; mt < 4; ++mt) {
            const int pr = (mt << 4) + m;
            const size_t rw = (size_t)(((pr & 3) << 10) + HO2 + (pr >> 2)) << 10;
            #pragma unroll
            for (int kt = 0; kt < 4; ++kt) {
                const int k = (wv << 7) + (kt << 5) + (quad << 3);
                split8(W_ih2 + rw + k, wh[mt][kt], wl[mt][kt]);
            }
        }
        for (int idx = tid; idx < 16384; idx += 512)
            gAcc[(idx >> 8) * GSTR + (idx & 255)] = 0.0f;
        __syncthreads();

        for (int it = 0; it < LOOP_END; ++it) {
            const int S = it;
            const int sP = it & 3;

            if (wv == 0 && it >= 3) {                    // out column t=it-3
                const float* pp = partials + (sP << 15) + (bx << 7);
                float s = pp[lane] + pp[lane + 64];
                s += __shfl_xor(s, 32); s += __shfl_xor(s, 16); s += __shfl_xor(s, 8);
                s += __shfl_xor(s, 4);  s += __shfl_xor(s, 2);  s += __shfl_xor(s, 1);
                if (lane == 0) st_f(&out[(bx << 9) + (it - 3)], bouts_s + s);
            }

            if (S >= 1 && S <= Tsz) {  // GEMM over h1(S-1)
                const _Float16* bhB = HBUF((S + 3) & 3, 0, 0);
                const _Float16* blB = HBUF((S + 3) & 3, 0, 1);
                const int lo_off = (wv << 11) + (lane << 3);
                #pragma unroll 1
                for (int bi = 0; bi < 16; ++bi) {
                    const int btl = (bi + (wv << 1)) & 15;
                    const _Float16* ph = bhB + (btl << 14) + lo_off;
                    const _Float16* pl = blB + (btl << 14) + lo_off;
                    half8 bh[4], bl[4];
                    #pragma unroll
                    for (int kt = 0; kt < 4; ++kt) {
                        bh[kt] = *(const half8*)(ph + (kt << 9));
                        bl[kt] = *(const half8*)(pl + (kt << 9));
                    }
                    f32x4 a0[4] = {(f32x4){0,0,0,0}, (f32x4){0,0,0,0},
                                   (f32x4){0,0,0,0}, (f32x4){0,0,0,0}};
                    f32x4 a1[4] = {(f32x4){0,0,0,0}, (f32x4){0,0,0,0},
                                   (f32x4){0,0,0,0}, (f32x4){0,0,0,0}};
                    #pragma unroll
                    for (int kt = 0; kt < 4; ++kt)
                        #pragma unroll
                        for (int mt = 0; mt < 4; ++mt) {
                            MFMA_V(a0[mt], wh[mt][kt], bh[kt]);
                            MFMA_V(a1[mt], wh[mt][kt], bl[kt]);
                            MFMA_V(a1[mt], wl[mt][kt], bh[kt]);
                        }
                    const int col = (btl << 4) + m;
                    #pragma unroll
                    for (int mt = 0; mt < 4; ++mt)
                        #pragma unroll
                        for (int r = 0; r < 4; ++r)
                            atomicAdd(&gAcc[((mt << 4) + (quad << 2) + r) * GSTR + col],
                                      a0[mt][r] + a1[mt][r] * INV2048);
                }
            }

            __syncthreads();

            if (S >= 1 && S <= Tsz) {  // export partial -> xbuf slot (S-1)&1, zero gAcc
                float* xb = xbuf + ((size_t)((((S - 1) & 1) << 6) | pa) << 14);
                for (int idx = tid; idx < 16384; idx += 512) {
                    const int p = idx >> 8, b = idx & 255;
                    st_f(&xb[idx], gAcc[p * GSTR + b]);
                    gAcc[p * GSTR + b] = 0.0f;
                }
            }

            step_barrier(arrX, flagX, bar1, dummyv, &relFlag_s,
                         isLead, xcc, nLead, nBlkX, (unsigned)(it + 1));
        }
    } else {
        // ==================== B BLOCKS: phh2 + combine + cell2 =============
        const int k0eB  = HO2 + (hg << 3);
        const int wofsB = ((b_ep >> 4) << 14) + ((k0eB >> 5) << 9)
                        + (((b_ep & 15) | (((k0eB >> 3) & 3) << 4)) << 3) + (k0eB & 7);
        half8 wh[4][4], wl[4][4];     // 128 regs/wave, M=64 rows, K-slice 128
        #pragma unroll
        for (int mt = 0; mt < 4; ++mt) {
            const int pr = (mt << 4) + m;
            const size_t rw = (size_t)(((pr & 3) << 10) + HO2 + (pr >> 2)) << 10;
            #pragma unroll
            for (int kt = 0; kt < 4; ++kt) {
                const int k = (wv << 7) + (kt << 5) + (quad << 3);
                split8(W_hh2 + rw + k, wh[mt][kt], wl[mt][kt]);
            }
        }
        for (int idx = tid; idx < 16384; idx += 512)
            gAcc[(idx >> 8) * GSTR + (idx & 255)] = bp[idx >> 8];
        __syncthreads();
        float cr[8] = {0, 0, 0, 0, 0, 0, 0, 0};

        for (int it = 0; it < LOOP_END; ++it) {
            const int S = it;
            const int sP = it & 3;

            if (wv == 0 && it >= 3) {                    // out column t=it-3
                const float* pp = partials + (sP << 15) + (bx << 7);
                float s = pp[lane] + pp[lane + 64];
                s += __shfl_xor(s, 32); s += __shfl_xor(s, 16); s += __shfl_xor(s, 8);
                s += __shfl_xor(s, 4);  s += __shfl_xor(s, 2);  s += __shfl_xor(s, 1);
                if (lane == 0) st_f(&out[(bx << 9) + (it - 3)], bouts_s + s);
            }

            if (S >= 2 && S <= Tsz + 1) {  // GEMM over h2(S-3) [slot (S+1)&3]
                const _Float16* bhB = HBUF((S + 1) & 3, 1, 0);
                const _Float16* blB = HBUF((S + 1) & 3, 1, 1);
                const int lo_off = (wv << 11) + (lane << 3);
                #pragma unroll 1
                for (int bi = 0; bi < 16; ++bi) {
                    const int btl = (bi + (wv << 1)) & 15;
                    const _Float16* ph = bhB + (btl << 14) + lo_off;
                    const _Float16* pl = blB + (btl << 14) + lo_off;
                    half8 bh[4], bl[4];
                    #pragma unroll
                    for (int kt = 0; kt < 4; ++kt) {
                        bh[kt] = *(const half8*)(ph + (kt << 9));
                        bl[kt] = *(const half8*)(pl + (kt << 9));
                    }
                    f32x4 a0[4] = {(f32x4){0,0,0,0}, (f32x4){0,0,0,0},
                                   (f32x4){0,0,0,0}, (f32x4){0,0,0,0}};
                    f32x4 a1[4] = {(f32x4){0,0,0,0}, (f32x4){0,0,0,0},
                                   (f32x4){0,0,0,0}, (f32x4){0,0,0,0}};
                    #pragma unroll
                    for (int kt = 0; kt < 4; ++kt)
                        #pragma unroll
                        for (int mt = 0; mt < 4; ++mt) {
                            MFMA_V(a0[mt], wh[mt][kt], bh[kt]);
                            MFMA_V(a1[mt], wh[mt][kt], bl[kt]);
                            MFMA_V(a1[mt], wl[mt][kt], bh[kt]);
                        }
                    const int col = (btl << 4) + m;
                    #pragma unroll
                    for (int mt = 0; mt < 4; ++mt)
                        #pragma unroll
                        for (int r = 0; r < 4; ++r)
                            atomicAdd(&gAcc[((mt << 4) + (quad << 2) + r) * GSTR + col],
                                      a0[mt][r] + a1[mt][r] * INV2048);
                }
            }

            __syncthreads();

            if (S >= 2 && S <= Tsz + 1) {  // combine + cell2(t=S-2) -> h2 @slot (S+2)&3
                const float* xb = xbuf + ((size_t)((((S - 2) & 1) << 6) | pa) << 14);
                half4 hA, hB, lA, lB;
                float po = 0.0f;
                #pragma unroll
                for (int j = 0; j < 8; ++j) {
                    const int p = ((hg << 3) + j) << 2;
                    const float gi = gAcc[(p + 0) * GSTR + b_ep] + agf_ld(xb + ((p + 0) << 8) + b_ep);
                    const float gf = gAcc[(p + 1) * GSTR + b_ep] + agf_ld(xb + ((p + 1) << 8) + b_ep);
                    const float gg = gAcc[(p + 2) * GSTR + b_ep] + agf_ld(xb + ((p + 2) << 8) + b_ep);
                    const float go = gAcc[(p + 3) * GSTR + b_ep] + agf_ld(xb + ((p + 3) << 8) + b_ep);
                    const float c  = sigm(gf) * cr[j] + sigm(gi) * tanh_f(gg);
                    cr[j] = c;
                    const float hn = sigm(go) * tanh_f(c);
                    const _Float16 hi16 = (_Float16)hn;
                    const _Float16 lo16 = (_Float16)((hn - (float)hi16) * 2048.0f);
                    if (j < 4) { hA[j] = hi16; lA[j] = lo16; }
                    else       { hB[j - 4] = hi16; lB[j - 4] = lo16; }
                    po += hn * woutp[(hg << 3) + j];
                }
                _Float16* dh = HBUF((S + 2) & 3, 1, 0) + wofsB;
                _Float16* dl = HBUF((S + 2) & 3, 1, 1) + wofsB;
                st_h4(dh, hA); st_h4(dh + 4, hB);
                st_h4(dl, lA); st_h4(dl + 4, lB);
                st_f(&partials[(((S + 1) & 3) << 15) + (b_ep << 7) + (pa << 1) + hg], po);
                #pragma unroll
                for (int p2 = hg << 5; p2 < (hg << 5) + 32; ++p2)
                    gAcc[p2 * GSTR + b_ep] = bp[p2];
            }

            step_barrier(arrX, flagX, bar1, dummyv, &relFlag_s,
                         isLead, xcc, nLead, nBlkX, (unsigned)(it + 1));
        }
    }
    #undef HBUF
}

// ---------------------------------------------------------------------------
extern "C" void kernel_launch(void* const* d_in, const int* in_sizes, int n_in,
                              void* d_out, int out_size, void* d_ws, size_t ws_size,
                              hipStream_t stream)
{
    const float* x     = (const float*)d_in[0];
    const float* W_ih1 = (const float*)d_in[1];
    const float* W_hh1 = (const float*)d_in[2];
    const float* b_ih1 = (const float*)d_in[3];
    const float* b_hh1 = (const float*)d_in[4];
    const float* W_ih2 = (const float*)d_in[5];
    const float* W_hh2 = (const float*)d_in[6];
    const float* b_ih2 = (const float*)d_in[7];
    const float* b_hh2 = (const float*)d_in[8];
    const float* W_out = (const float*)d_in[9];
    const float* b_out = (const float*)d_in[10];
    float* out = (float*)d_out;
    char*  ws  = (char*)d_ws;

    void* args[] = {
        (void*)&x,
        (void*)&W_ih1, (void*)&W_hh1, (void*)&b_ih1, (void*)&b_hh1,
        (void*)&W_ih2, (void*)&W_hh2, (void*)&b_ih2, (void*)&b_hh2,
        (void*)&W_out, (void*)&b_out, (void*)&out, (void*)&ws,
    };
    hipLaunchCooperativeKernel((const void*)lstm_persist,
                               dim3(256), dim3(512), args, 0, stream);
}